// Round 12
// baseline (146.648 us; speedup 1.0000x reference)
//
#include <hip/hip_runtime.h>
#include <hip/hip_bf16.h>

#define BATCH 32
#define LL 512
#define DD 768
#define EPSC 1e-5f

typedef __attribute__((ext_vector_type(8))) short bf16x8;
typedef __attribute__((ext_vector_type(4))) float f32x4;

// ---------------------------------------------------------------------------
// Kernel 1 (fused prep): block = (l-block of 64 rows, batch). Phase 1 computes
// w[l] = (eps + sum_d x^2)^(1/4) in-register (4 lanes per row, 2 shfl).
// Phase 2 = the harness-verified 64x64 LDS transpose body, iterated over the
// 12 d-tiles (x re-reads come from L2). ~12 us = its 75 MB HBM floor.
// ---------------------------------------------------------------------------
__global__ __launch_bounds__(256) void k_prep(const float* __restrict__ x,
                                              ushort* __restrict__ yt) {
    __shared__ float tile[64][65];
    __shared__ float svec[64];
    int lb = blockIdx.x;                              // [0,8) l-block
    int b = blockIdx.y;
    int l0 = lb * 64;
    int t = threadIdx.x;

    // Phase 1: row r = t>>2 (0..63), quarter q = t&3 covers 192 floats.
    {
        int r = t >> 2, q = t & 3;
        const float4* xr = (const float4*)(x + ((size_t)b * LL + l0 + r) * DD) + q * 48;
        float sum = 0.f;
#pragma unroll 8
        for (int i = 0; i < 48; i++) {
            float4 v = xr[i];
            sum += v.x * v.x + v.y * v.y + v.z * v.z + v.w * v.w;
        }
        sum += __shfl_xor(sum, 1, 64);
        sum += __shfl_xor(sum, 2, 64);
        if (q == 0) svec[r] = sqrtf(sqrtf(EPSC + sum));
    }
    __syncthreads();

    // Phase 2: 12 x (load 64x64 tile -> transpose+scale -> bf16 store).
    const float* xb = x + ((size_t)b * LL + l0) * DD;
    int f = t & 15, lr0 = t >> 4;                     // f: float4 col, lr0: row
    int lc = t & 7, dl0 = t >> 3;                     // lc: l-chunk, dl0: d row
    for (int dt = 0; dt < 12; dt++) {
        int d0 = dt * 64;
#pragma unroll
        for (int r = 0; r < 4; r++) {
            int l = lr0 + r * 16;
            float4 v = *(const float4*)(xb + (size_t)l * DD + d0 + f * 4);
#pragma unroll
            for (int j = 0; j < 4; j++)
                tile[l][f * 4 + j] = ((const float*)&v)[j];
        }
        __syncthreads();
        ushort* yp = yt + ((size_t)b * DD + d0) * LL + l0;
#pragma unroll
        for (int it = 0; it < 2; it++) {
            int d = dl0 + it * 32;
            bf16x8 w;
#pragma unroll
            for (int j = 0; j < 8; j++) {
                int l = lc * 8 + j;
                float v = tile[l][d] * svec[l];
                __hip_bfloat16 h = __float2bfloat16(v);
                w[j] = *(short*)&h;
            }
            *(bf16x8*)(yp + (size_t)d * LL + lc * 8) = w;
        }
        __syncthreads();
    }
}

// ---------------------------------------------------------------------------
// Kernel 2: C[b] = Yt[b]*Yt[b]^T, symmetric. FULL 6x6 tile grid (no triangle
// decomposition): block (tm,tn) computes D = A_tm * B_tn^T and, exploiting
// symmetry, writes it to output tile (tn,tm) -- the direction in which the
// MFMA D-layout gives lane-contiguous float4 stores. Every output element is
// written exactly once, with ZERO scalar stores (kills the ~11M-instruction
// scalar-epilogue tax every triangular variant paid). Compute doubles, but
// MFMA (9.3us) and LDS-read (11.5us) stay under the 11.7us HBM-write floor.
// 1152 blocks, 32KB LDS (BK=32 dbuf), VGPR ~84 -> 5 blocks/CU cap: the whole
// grid is co-resident in ONE dispatch wave (zero tail). Pipeline/staging/
// swizzle verbatim from the passed R11 kernel: single-barrier dbuf, phys
// 16B-chunk c of row r holds logical chunk c^(r&3), pre-swizzled global
// source (linear LDS dest), frag read same XOR (rule #21).
// ---------------------------------------------------------------------------
__global__ __launch_bounds__(256) void k_gemm(const ushort* __restrict__ yt,
                                              float* __restrict__ out) {
    __shared__ ushort At[2][128 * 32];                // 2 x 8 KB
    __shared__ ushort Bt[2][128 * 32];
    int i = blockIdx.x;                               // [0, 1152)
    int xcd = i & 7, slot = i >> 3;                   // XCD round-robin
    int b = xcd + 8 * (slot / 36);                    // 4 batches per XCD
    int p = slot % 36;
    int tm = p / 6, tn = p % 6;                       // full grid
    int m0 = tm * 128, n0 = tn * 128;
    int tid = threadIdx.x;
    int wave = tid >> 6, lane = tid & 63;
    int wr = wave >> 1, wc = wave & 1;                // 2x2 waves, 64x64 each
    const ushort* yb = yt + (size_t)b * DD * LL;

    f32x4 acc[4][4];
#pragma unroll
    for (int ii = 0; ii < 4; ii++)
#pragma unroll
        for (int j = 0; j < 4; j++) acc[ii][j] = (f32x4){0.f, 0.f, 0.f, 0.f};

    // Staging: per matrix per buffer = 128 rows x 4 chunks = 512 16B-slots;
    // 256 threads -> 2 issues. Slot s = is*256 + tid: row = s>>2, physical
    // chunk = s&3, logical chunk = (s&3)^(row&3) (pre-swizzled source).
    const ushort* gA[2];
    const ushort* gB[2];
    int ldsOff[2];
#pragma unroll
    for (int is = 0; is < 2; is++) {
        int s = is * 256 + tid;
        int row = s >> 2;
        int lc = (s & 3) ^ (row & 3);
        gA[is] = yb + (size_t)(m0 + row) * LL + lc * 8;
        gB[is] = yb + (size_t)(n0 + row) * LL + lc * 8;
        ldsOff[is] = (is * 256 + wave * 64) * 8;      // wave-uniform +lane*16B
    }

    // Frag read: lane (fr, ks4); row r's logical chunk ks4 at phys ks4^(r&3).
    int fr = lane & 15, ks4 = lane >> 4;

#define STAGE(buf, ks) do {                                                   \
        int k0_ = (ks) * 32;                                                  \
        _Pragma("unroll")                                                     \
        for (int is = 0; is < 2; is++) {                                      \
            __builtin_amdgcn_global_load_lds(                                 \
                (const __attribute__((address_space(1))) void*)(gA[is] + k0_),\
                (__attribute__((address_space(3))) void*)(At[buf] + ldsOff[is]),\
                16, 0, 0);                                                    \
            __builtin_amdgcn_global_load_lds(                                 \
                (const __attribute__((address_space(1))) void*)(gB[is] + k0_),\
                (__attribute__((address_space(3))) void*)(Bt[buf] + ldsOff[is]),\
                16, 0, 0);                                                    \
        }                                                                     \
    } while (0)

    STAGE(0, 0);
    __syncthreads();                                  // buf0 ready
    for (int ks = 0; ks < 16; ks++) {
        int cur = ks & 1;
        if (ks < 15) STAGE(cur ^ 1, ks + 1);          // prefetch next tile
        const ushort* Ab = At[cur];
        const ushort* Bb = Bt[cur];
        bf16x8 af[4], bg[4];
#pragma unroll
        for (int ii = 0; ii < 4; ii++) {
            int mr = wr * 64 + ii * 16 + fr;
            int nr = wc * 64 + ii * 16 + fr;
            af[ii] = *(const bf16x8*)(Ab + mr * 32 + (ks4 ^ (mr & 3)) * 8);
            bg[ii] = *(const bf16x8*)(Bb + nr * 32 + (ks4 ^ (nr & 3)) * 8);
        }
#pragma unroll
        for (int ii = 0; ii < 4; ii++)
#pragma unroll
            for (int j = 0; j < 4; j++)
                acc[ii][j] = __builtin_amdgcn_mfma_f32_16x16x32_bf16(
                    af[ii], bg[j], acc[ii][j], 0, 0, 0);
        if (ks < 15) __syncthreads();                 // drain stage + handoff
    }
#undef STAGE

    // Epilogue: symmetric write only. D[m=ii*16+ks4*4+r][n=j*16+fr] goes to
    // C[n_global][m_global] (float4 along m) -- valid by symmetry; over the
    // full grid every output tile is covered exactly once. 16 f4/lane total.
    float* op = out + (size_t)b * DD * DD;
#pragma unroll
    for (int ii = 0; ii < 4; ii++) {
        int colb = m0 + wr * 64 + ii * 16 + ks4 * 4;
#pragma unroll
        for (int j = 0; j < 4; j++) {
            int row = n0 + wc * 64 + j * 16 + fr;
            float4 v = {acc[ii][j][0], acc[ii][j][1], acc[ii][j][2], acc[ii][j][3]};
            *(float4*)(op + (size_t)row * DD + colb) = v;
        }
    }
}

// ---------------------------------------------------------------------------
extern "C" void kernel_launch(void* const* d_in, const int* in_sizes, int n_in,
                              void* d_out, int out_size, void* d_ws, size_t ws_size,
                              hipStream_t stream) {
    const float* x = (const float*)d_in[0];
    ushort* yt = (ushort*)d_ws;                                     // 25.2 MB bf16

    k_prep<<<dim3(LL / 64, BATCH), 256, 0, stream>>>(x, yt);
    k_gemm<<<dim3(36 * BATCH), 256, 0, stream>>>(yt, (float*)d_out);
}